// Round 4
// baseline (906.262 us; speedup 1.0000x reference)
//
#include <hip/hip_runtime.h>
#include <stdint.h>

// H2GCN forward on MI355X (gfx950). Round 4:
//  - W_embed/W1/W2 pre-split into bf16 hi/lo ONCE (prep kernels) -> embed/final
//    lose the per-k-step split8 VALU storm (was ~120 VALU/k-step vs 12 MFMA).
//  - k_embed software-pipelines the x row loads.
//  - SPMM inner loop x8 unroll (8 gathers in flight).

typedef __bf16 bf16x8 __attribute__((ext_vector_type(8)));
typedef float  f32x4  __attribute__((ext_vector_type(4)));

#define NN   100000
#define EE   800000
#define IND  512
#define HID  64
#define ZD   320
#define CLS  40
#define NCH  98          // ceil(NN/1024)
#define NTILE (NN/16)    // 6250 row tiles of 16

static __device__ __forceinline__ float bf2f(unsigned short s) {
  unsigned int u = ((unsigned int)s) << 16;
  return __builtin_bit_cast(float, u);
}
static __device__ __forceinline__ unsigned short f2bf(float f) {
  unsigned int u = __builtin_bit_cast(unsigned int, f);
  u += 0x7FFFu + ((u >> 16) & 1u);   // RNE
  return (unsigned short)(u >> 16);
}
static __device__ __forceinline__ float ldsc(const void* p, int i, int fm) {
  return fm ? ((const float*)p)[i] : bf2f(((const unsigned short*)p)[i]);
}
static __device__ __forceinline__ float i2f(int v) { return __builtin_bit_cast(float, v); }
// split two f32x4 regs into hi/lo bf16 fragments
static __device__ __forceinline__ void split8r(f32x4 u0, f32x4 u1, bf16x8& hi, bf16x8& lo) {
  #pragma unroll
  for (int j = 0; j < 4; ++j) {
    float v0 = u0[j], v1 = u1[j];
    __bf16 h0 = (__bf16)v0, h1 = (__bf16)v1;
    hi[j] = h0;     lo[j] = (__bf16)(v0 - (float)h0);
    hi[4 + j] = h1; lo[4 + j] = (__bf16)(v1 - (float)h1);
  }
}

// ---------------- dtype probe ----------------
__global__ void k_probe(const unsigned short* __restrict__ xs,
                        const int* __restrict__ ei, int* __restrict__ flags) {
  __shared__ int cnt_big, cnt_nz;
  if (threadIdx.x == 0) { cnt_big = 0; cnt_nz = 0; }
  __syncthreads();
  unsigned short u = xs[threadIdx.x];
  int expf = (u >> 7) & 0xFF;
  if (expf >= 0x8D) atomicAdd(&cnt_big, 1);      // |bf16| >= 2^14 (or NaN/Inf)
  if (threadIdx.x < 128 && ei[2 * threadIdx.x + 1] != 0) atomicAdd(&cnt_nz, 1);
  __syncthreads();
  if (threadIdx.x == 0) {
    flags[0] = (cnt_big >= 2) ? 1 : 0;
    flags[1] = (cnt_nz < 64) ? 1 : 0;
  }
}

// ---------------- weight pre-split: f32 (or bf16) -> bf16 hi/lo --------------
__global__ void k_wsplit(const void* __restrict__ Wv, const int* __restrict__ flags,
                         int n, unsigned short* __restrict__ hi,
                         unsigned short* __restrict__ lo) {
  int i = blockIdx.x * 256 + threadIdx.x;
  if (i >= n) return;
  float v = ldsc(Wv, i, flags[0]);
  __bf16 h = (__bf16)v;
  hi[i] = __builtin_bit_cast(unsigned short, h);
  __bf16 l = (__bf16)(v - (float)h);
  lo[i] = __builtin_bit_cast(unsigned short, l);
}

// ---------------- graph build ----------------
__global__ void k_deg(const int* __restrict__ ei, const int* __restrict__ flags,
                      int* __restrict__ deg) {
  int es = flags[1] + 1;
  int e = blockIdx.x * 256 + threadIdx.x;
  if (e >= EE) return;
  int r = ei[(size_t)e * es], c = ei[(size_t)(EE + e) * es];
  if (r != c) { atomicAdd(&deg[r], 1); atomicAdd(&deg[c], 1); }
}

__global__ void k_chunksum(const int* __restrict__ deg, int* __restrict__ csum) {
  __shared__ int sd[1024];
  int i = blockIdx.x * 1024 + threadIdx.x;
  sd[threadIdx.x] = (i < NN) ? deg[i] : 0;
  __syncthreads();
  for (int s = 512; s > 0; s >>= 1) {
    if (threadIdx.x < s) sd[threadIdx.x] += sd[threadIdx.x + s];
    __syncthreads();
  }
  if (threadIdx.x == 0) csum[blockIdx.x] = sd[0];
}

__global__ void k_scanchunks(int* __restrict__ csum, int* __restrict__ total) {
  if (threadIdx.x == 0) {
    int acc = 0;
    for (int i = 0; i < NCH; ++i) { int v = csum[i]; csum[i] = acc; acc += v; }
    total[0] = acc;
  }
}

__global__ void k_offs(const int* __restrict__ deg, const int* __restrict__ cbase,
                       int* __restrict__ offs, float* __restrict__ dinv) {
  __shared__ int sd[1024];
  int i = blockIdx.x * 1024 + threadIdx.x;
  int v = (i < NN) ? deg[i] : 0;
  sd[threadIdx.x] = v;
  __syncthreads();
  for (int s = 1; s < 1024; s <<= 1) {
    int t = (threadIdx.x >= s) ? sd[threadIdx.x - s] : 0;
    __syncthreads();
    sd[threadIdx.x] += t;
    __syncthreads();
  }
  if (i < NN) {
    offs[i] = cbase[blockIdx.x] + sd[threadIdx.x] - v;
    dinv[i] = (v > 0) ? rsqrtf((float)v) : 0.f;
  }
}

__global__ void k_fill(const int* __restrict__ ei, const int* __restrict__ flags,
                       const int* __restrict__ offs,
                       int* __restrict__ fill, const float* __restrict__ dinv,
                       int2* __restrict__ ep) {
  int es = flags[1] + 1;
  int e = blockIdx.x * 256 + threadIdx.x;
  if (e >= EE) return;
  int r = ei[(size_t)e * es], c = ei[(size_t)(EE + e) * es];
  if (r == c) return;
  float w = dinv[r] * dinv[c];
  int wb = __builtin_bit_cast(int, w);
  int p = offs[r] + atomicAdd(&fill[r], 1);
  ep[p] = make_int2(c, wb);
  int q = offs[c] + atomicAdd(&fill[c], 1);
  ep[q] = make_int2(r, wb);
}

// ---------------- embed GEMM: hraw = relu(x @ W^T + b) + BN partial sums -----
__global__ __launch_bounds__(256) void k_embed(
    const void* __restrict__ xv,
    const unsigned short* __restrict__ whi, const unsigned short* __restrict__ wlo,
    const void* __restrict__ bEv, const int* __restrict__ flags,
    float* __restrict__ hraw, float* __restrict__ bnsum, float* __restrict__ bnsq) {
  __shared__ float s_sum[64], s_sq[64];
  const int fm = flags[0];
  const int wave = threadIdx.x >> 6, lane = threadIdx.x & 63;
  const int l15 = lane & 15, quad = lane >> 4;
  const int gid = blockIdx.x * 4 + wave;
  const bool valid = gid < NTILE;
  if (threadIdx.x < 64) { s_sum[threadIdx.x] = 0.f; s_sq[threadIdx.x] = 0.f; }
  __syncthreads();
  if (valid) {
    const int rb = gid * 16;
    f32x4 acc[4] = {};
    if (fm) {
      const float* xr = (const float*)xv + (size_t)(rb + l15) * IND + quad * 8;
      f32x4 u0 = *(const f32x4*)(xr);
      f32x4 u1 = *(const f32x4*)(xr + 4);
      for (int ks = 0; ks < 16; ++ks) {
        f32x4 n0 = {}, n1 = {};
        if (ks < 15) {
          n0 = *(const f32x4*)(xr + (ks + 1) * 32);
          n1 = *(const f32x4*)(xr + (ks + 1) * 32 + 4);
        }
        bf16x8 ahi, alo;
        split8r(u0, u1, ahi, alo);
        #pragma unroll
        for (int nt = 0; nt < 4; ++nt) {
          size_t wb = (size_t)(nt * 16 + l15) * IND + ks * 32 + quad * 8;
          bf16x8 bhi = *(const bf16x8*)(whi + wb);
          bf16x8 blo = *(const bf16x8*)(wlo + wb);
          acc[nt] = __builtin_amdgcn_mfma_f32_16x16x32_bf16(ahi, bhi, acc[nt], 0, 0, 0);
          acc[nt] = __builtin_amdgcn_mfma_f32_16x16x32_bf16(alo, bhi, acc[nt], 0, 0, 0);
          acc[nt] = __builtin_amdgcn_mfma_f32_16x16x32_bf16(ahi, blo, acc[nt], 0, 0, 0);
        }
        u0 = n0; u1 = n1;
      }
    } else {
      const unsigned short* xr = (const unsigned short*)xv + (size_t)(rb + l15) * IND + quad * 8;
      for (int ks = 0; ks < 16; ++ks) {
        bf16x8 a = *(const bf16x8*)(xr + ks * 32);
        #pragma unroll
        for (int nt = 0; nt < 4; ++nt) {
          bf16x8 b = *(const bf16x8*)(whi + (size_t)(nt * 16 + l15) * IND + ks * 32 + quad * 8);
          acc[nt] = __builtin_amdgcn_mfma_f32_16x16x32_bf16(a, b, acc[nt], 0, 0, 0);
        }
      }
    }
    #pragma unroll
    for (int nt = 0; nt < 4; ++nt) {
      int n = nt * 16 + l15;
      float bb = ldsc(bEv, n, fm);
      float ps = 0.f, pq = 0.f;
      #pragma unroll
      for (int r = 0; r < 4; ++r) {
        float v = fmaxf(acc[nt][r] + bb, 0.f);
        hraw[(size_t)(rb + quad * 4 + r) * 64 + n] = v;
        ps += v; pq += v * v;
      }
      ps += __shfl_xor(ps, 16); pq += __shfl_xor(pq, 16);
      ps += __shfl_xor(ps, 32); pq += __shfl_xor(pq, 32);
      if (quad == 0) { atomicAdd(&s_sum[n], ps); atomicAdd(&s_sq[n], pq); }
    }
  }
  __syncthreads();
  if (threadIdx.x < 64) {
    atomicAdd(&bnsum[threadIdx.x], s_sum[threadIdx.x]);
    atomicAdd(&bnsq[threadIdx.x], s_sq[threadIdx.x]);
  }
}

__global__ void k_bnfin(const float* __restrict__ bnsum, const float* __restrict__ bnsq,
                        const void* __restrict__ gv, const void* __restrict__ bv,
                        const int* __restrict__ flags, float* __restrict__ ab) {
  int c = threadIdx.x;
  int fm = flags[0];
  if (c < 64) {
    float mu = bnsum[c] * (1.0f / (float)NN);
    float var = bnsq[c] * (1.0f / (float)NN) - mu * mu;
    float a = ldsc(gv, c, fm) / sqrtf(var + 1e-5f);
    float b = ldsc(bv, c, fm) - mu * a;
    ab[c] = a; ab[64 + c] = b;
  }
}

// ---------------- SPMM kernels (x8-unrolled gather, 8 accumulators) ----------
// SPMM1: gather raw h; z0 = BN(hraw[r]); z1 = a*Sum(w*hraw) + b*Sum(w); diag2 = Sum(w^2)
__global__ __launch_bounds__(256) void k_sp1(
    const int* __restrict__ offs, const int2* __restrict__ ep,
    const float* __restrict__ hraw, const float* __restrict__ bnab,
    float* __restrict__ diag2, float* __restrict__ z) {
  const int r = blockIdx.x * 4 + (threadIdx.x >> 6);
  const int lane = threadIdx.x & 63;
  if (r >= NN) return;
  int s = offs[r], e = offs[r + 1];
  float a[8] = {}; float sw = 0, sq = 0;
  int j = s;
  for (; j + 8 <= e; j += 8) {
    int2 p[8];
    #pragma unroll
    for (int t = 0; t < 8; ++t) p[t] = ep[j + t];
    float xv[8];
    #pragma unroll
    for (int t = 0; t < 8; ++t) xv[t] = hraw[(size_t)p[t].x * 64 + lane];
    #pragma unroll
    for (int t = 0; t < 8; ++t) {
      float w = i2f(p[t].y);
      a[t] = fmaf(w, xv[t], a[t]);
      sw += w; sq = fmaf(w, w, sq);
    }
  }
  if (j + 4 <= e) {
    int2 p[4];
    #pragma unroll
    for (int t = 0; t < 4; ++t) p[t] = ep[j + t];
    #pragma unroll
    for (int t = 0; t < 4; ++t) {
      float w = i2f(p[t].y);
      a[t] = fmaf(w, hraw[(size_t)p[t].x * 64 + lane], a[t]);
      sw += w; sq = fmaf(w, w, sq);
    }
    j += 4;
  }
  for (; j < e; ++j) {
    int2 p = ep[j];
    float w = i2f(p.y);
    a[0] = fmaf(w, hraw[(size_t)p.x * 64 + lane], a[0]);
    sw += w; sq = fmaf(w, w, sq);
  }
  float acc = ((a[0] + a[1]) + (a[2] + a[3])) + ((a[4] + a[5]) + (a[6] + a[7]));
  float ga = bnab[lane], gb = bnab[64 + lane];
  size_t zr = (size_t)r * ZD;
  z[zr + lane] = fmaf(ga, hraw[(size_t)r * 64 + lane], gb);
  z[zr + 64 + lane] = ga * acc + gb * sw;
  if (lane == 0) diag2[r] = sq;
}

// SPMM2: gather h1 (z+64); h2 = acc - diag2*z0; write z2 and cur = h1[r] + h2
__global__ __launch_bounds__(256) void k_sp2(
    const int* __restrict__ offs, const int2* __restrict__ ep,
    const float* __restrict__ diag2, float* __restrict__ z,
    float* __restrict__ cur) {
  const int r = blockIdx.x * 4 + (threadIdx.x >> 6);
  const int lane = threadIdx.x & 63;
  if (r >= NN) return;
  int s = offs[r], e = offs[r + 1];
  const float* xin = z + 64;
  float a[8] = {};
  int j = s;
  for (; j + 8 <= e; j += 8) {
    int2 p[8];
    #pragma unroll
    for (int t = 0; t < 8; ++t) p[t] = ep[j + t];
    float xv[8];
    #pragma unroll
    for (int t = 0; t < 8; ++t) xv[t] = xin[(size_t)p[t].x * ZD + lane];
    #pragma unroll
    for (int t = 0; t < 8; ++t) a[t] = fmaf(i2f(p[t].y), xv[t], a[t]);
  }
  if (j + 4 <= e) {
    int2 p[4];
    #pragma unroll
    for (int t = 0; t < 4; ++t) p[t] = ep[j + t];
    #pragma unroll
    for (int t = 0; t < 4; ++t) a[t] = fmaf(i2f(p[t].y), xin[(size_t)p[t].x * ZD + lane], a[t]);
    j += 4;
  }
  for (; j < e; ++j) {
    int2 p = ep[j];
    a[0] = fmaf(i2f(p.y), xin[(size_t)p.x * ZD + lane], a[0]);
  }
  float acc = ((a[0] + a[1]) + (a[2] + a[3])) + ((a[4] + a[5]) + (a[6] + a[7]));
  size_t zr = (size_t)r * ZD;
  float h2 = acc - diag2[r] * z[zr + lane];
  z[zr + 128 + lane] = h2;
  cur[(size_t)r * 64 + lane] = z[zr + 64 + lane] + h2;
}

// SPMM3/4 generic: gather xin (stride xs); y = acc [- diag2*corr64]; write yout
__global__ __launch_bounds__(256) void k_spg(
    const int* __restrict__ offs, const int2* __restrict__ ep,
    const float* __restrict__ xin, long xs,
    const float* __restrict__ diag2, const float* __restrict__ corr64,
    float* __restrict__ yout) {
  const int r = blockIdx.x * 4 + (threadIdx.x >> 6);
  const int lane = threadIdx.x & 63;
  if (r >= NN) return;
  int s = offs[r], e = offs[r + 1];
  float a[8] = {};
  int j = s;
  for (; j + 8 <= e; j += 8) {
    int2 p[8];
    #pragma unroll
    for (int t = 0; t < 8; ++t) p[t] = ep[j + t];
    float xv[8];
    #pragma unroll
    for (int t = 0; t < 8; ++t) xv[t] = xin[(size_t)p[t].x * xs + lane];
    #pragma unroll
    for (int t = 0; t < 8; ++t) a[t] = fmaf(i2f(p[t].y), xv[t], a[t]);
  }
  if (j + 4 <= e) {
    int2 p[4];
    #pragma unroll
    for (int t = 0; t < 4; ++t) p[t] = ep[j + t];
    #pragma unroll
    for (int t = 0; t < 4; ++t) a[t] = fmaf(i2f(p[t].y), xin[(size_t)p[t].x * xs + lane], a[t]);
    j += 4;
  }
  for (; j < e; ++j) {
    int2 p = ep[j];
    a[0] = fmaf(i2f(p.y), xin[(size_t)p.x * xs + lane], a[0]);
  }
  float acc = ((a[0] + a[1]) + (a[2] + a[3])) + ((a[4] + a[5]) + (a[6] + a[7]));
  if (corr64) acc -= diag2[r] * corr64[(size_t)r * 64 + lane];
  yout[(size_t)r * ZD + lane] = acc;
}

// ---------------- final: out = relu(z @ W1^T + b1) @ W2^T + b2 ----------------
__global__ __launch_bounds__(256) void k_final(
    const float* __restrict__ z,
    const unsigned short* __restrict__ w1hi, const unsigned short* __restrict__ w1lo,
    const void* __restrict__ b1v,
    const unsigned short* __restrict__ w2hi, const unsigned short* __restrict__ w2lo,
    const void* __restrict__ b2v,
    const int* __restrict__ flags, void* __restrict__ outv) {
  __shared__ float tls[4][16][68];
  const int fm = flags[0];
  const int wave = threadIdx.x >> 6, lane = threadIdx.x & 63;
  const int l15 = lane & 15, quad = lane >> 4;
  const int gid = blockIdx.x * 4 + wave;
  const bool valid = gid < NTILE;
  if (valid) {
    const int rb = gid * 16;
    f32x4 acc[4] = {};
    const float* zr = z + (size_t)(rb + l15) * ZD + quad * 8;
    f32x4 u0 = *(const f32x4*)(zr);
    f32x4 u1 = *(const f32x4*)(zr + 4);
    for (int ks = 0; ks < 10; ++ks) {
      f32x4 n0 = {}, n1 = {};
      if (ks < 9) {
        n0 = *(const f32x4*)(zr + (ks + 1) * 32);
        n1 = *(const f32x4*)(zr + (ks + 1) * 32 + 4);
      }
      bf16x8 ahi, alo;
      split8r(u0, u1, ahi, alo);
      #pragma unroll
      for (int nt = 0; nt < 4; ++nt) {
        size_t wb = (size_t)(nt * 16 + l15) * ZD + ks * 32 + quad * 8;
        bf16x8 bhi = *(const bf16x8*)(w1hi + wb);
        bf16x8 blo = *(const bf16x8*)(w1lo + wb);
        acc[nt] = __builtin_amdgcn_mfma_f32_16x16x32_bf16(ahi, bhi, acc[nt], 0, 0, 0);
        acc[nt] = __builtin_amdgcn_mfma_f32_16x16x32_bf16(alo, bhi, acc[nt], 0, 0, 0);
        acc[nt] = __builtin_amdgcn_mfma_f32_16x16x32_bf16(ahi, blo, acc[nt], 0, 0, 0);
      }
      u0 = n0; u1 = n1;
    }
    #pragma unroll
    for (int nt = 0; nt < 4; ++nt) {
      int n = nt * 16 + l15;
      float bb = ldsc(b1v, n, fm);
      #pragma unroll
      for (int r = 0; r < 4; ++r)
        tls[wave][quad * 4 + r][n] = fmaxf(acc[nt][r] + bb, 0.f);
    }
  }
  __syncthreads();
  if (valid) {
    const int rb = gid * 16;
    f32x4 acc2[3] = {};
    #pragma unroll
    for (int ks = 0; ks < 2; ++ks) {
      bf16x8 ahi, alo;
      #pragma unroll
      for (int j = 0; j < 8; ++j) {
        float v = tls[wave][l15][ks * 32 + quad * 8 + j];
        __bf16 h = (__bf16)v;
        ahi[j] = h; alo[j] = (__bf16)(v - (float)h);
      }
      #pragma unroll
      for (int nt = 0; nt < 3; ++nt) {
        int n = nt * 16 + l15;
        bf16x8 bhi = {}, blo = {};
        if (n < CLS) {
          size_t wb = (size_t)n * HID + ks * 32 + quad * 8;
          bhi = *(const bf16x8*)(w2hi + wb);
          blo = *(const bf16x8*)(w2lo + wb);
        }
        acc2[nt] = __builtin_amdgcn_mfma_f32_16x16x32_bf16(ahi, bhi, acc2[nt], 0, 0, 0);
        acc2[nt] = __builtin_amdgcn_mfma_f32_16x16x32_bf16(alo, bhi, acc2[nt], 0, 0, 0);
        acc2[nt] = __builtin_amdgcn_mfma_f32_16x16x32_bf16(ahi, blo, acc2[nt], 0, 0, 0);
      }
    }
    #pragma unroll
    for (int nt = 0; nt < 3; ++nt) {
      int n = nt * 16 + l15;
      if (n < CLS) {
        float bb = ldsc(b2v, n, fm);
        #pragma unroll
        for (int r = 0; r < 4; ++r) {
          float v = acc2[nt][r] + bb;
          size_t oi = (size_t)(rb + quad * 4 + r) * CLS + n;
          if (fm) ((float*)outv)[oi] = v;
          else    ((unsigned short*)outv)[oi] = f2bf(v);
        }
      }
    }
  }
}

extern "C" void kernel_launch(void* const* d_in, const int* in_sizes, int n_in,
                              void* d_out, int out_size, void* d_ws, size_t ws_size,
                              hipStream_t stream) {
  (void)in_sizes; (void)n_in; (void)out_size; (void)ws_size;
  const void* x   = d_in[0];
  const int*  ei  = (const int*)d_in[1];
  const void* WE  = d_in[2];
  const void* bE  = d_in[3];
  const void* gam = d_in[4];
  const void* bet = d_in[5];
  const void* W1  = d_in[6];
  const void* b1  = d_in[7];
  const void* W2  = d_in[8];
  const void* b2  = d_in[9];

  float* wsf = (float*)d_ws;
  int*   wsi = (int*)d_ws;
  // word-offset layout; total ~168.6 MB
  int*   deg   = wsi + 0;          // NN (zeroed)
  int*   fill  = wsi + 100000;     // NN (zeroed)
  float* bnsum = wsf + 200000;     // 64 (zeroed)
  float* bnsq  = wsf + 200064;     // 64 (zeroed)
  int*   flags = wsi + 200128;     // 8
  float* bnab  = wsf + 200136;     // 128
  float* dinv  = wsf + 200264;     // NN
  int*   offs  = wsi + 300264;     // NN+1
  int*   cbase = wsi + 400272;     // NCH (pad to 400384)
  unsigned short* whi  = (unsigned short*)(wsi + 400384);  // 64*512 bf16
  unsigned short* wlo  = (unsigned short*)(wsi + 416768);
  unsigned short* w1hi = (unsigned short*)(wsi + 433152);  // 64*320
  unsigned short* w1lo = (unsigned short*)(wsi + 443392);
  unsigned short* w2hi = (unsigned short*)(wsi + 453632);  // 40*64
  unsigned short* w2lo = (unsigned short*)(wsi + 454912);
  int2*  ep    = (int2*)(wsi + 456192);   // 1.6M edges
  float* diag2 = wsf + 3656192;    // NN
  float* hraw  = wsf + 3756192;    // NN*64 (aliased as `cur` after SPMM1)
  float* z     = wsf + 10156192;   // NN*ZD
  float* cur   = hraw;

  hipMemsetAsync(d_ws, 0, (size_t)200128 * 4, stream);

  k_probe     <<<1, 256, 0, stream>>>((const unsigned short*)x, ei, flags);
  k_wsplit    <<<(64 * IND + 255) / 256, 256, 0, stream>>>(WE, flags, 64 * IND, whi, wlo);
  k_wsplit    <<<(64 * ZD + 255) / 256, 256, 0, stream>>>(W1, flags, 64 * ZD, w1hi, w1lo);
  k_wsplit    <<<(CLS * HID + 255) / 256, 256, 0, stream>>>(W2, flags, CLS * HID, w2hi, w2lo);

  k_deg       <<<EE / 256, 256, 0, stream>>>(ei, flags, deg);
  k_chunksum  <<<NCH, 1024, 0, stream>>>(deg, cbase);
  k_scanchunks<<<1, 64, 0, stream>>>(cbase, offs + NN);
  k_offs      <<<NCH, 1024, 0, stream>>>(deg, cbase, offs, dinv);
  k_fill      <<<EE / 256, 256, 0, stream>>>(ei, flags, offs, fill, dinv, ep);

  k_embed     <<<(NTILE + 3) / 4, 256, 0, stream>>>(x, whi, wlo, bE, flags, hraw, bnsum, bnsq);
  k_bnfin     <<<1, 64, 0, stream>>>(bnsum, bnsq, gam, bet, flags, bnab);

  k_sp1<<<NN / 4, 256, 0, stream>>>(offs, ep, hraw, bnab, diag2, z);
  k_sp2<<<NN / 4, 256, 0, stream>>>(offs, ep, diag2, z, cur);
  k_spg<<<NN / 4, 256, 0, stream>>>(offs, ep, cur, 64, diag2, nullptr, z + 192);
  k_spg<<<NN / 4, 256, 0, stream>>>(offs, ep, z + 192, ZD, diag2, cur, z + 256);

  k_final<<<(NTILE + 3) / 4, 256, 0, stream>>>(z, w1hi, w1lo, b1, w2hi, w2lo, b2,
                                               flags, d_out);
}

// Round 5
// 865.672 us; speedup vs baseline: 1.0469x; 1.0469x over previous
//
#include <hip/hip_runtime.h>
#include <stdint.h>

// H2GCN forward on MI355X (gfx950). Round 5:
//  - k_embed: M=64 rows/wave (4 tiles share each W hi/lo fragment) -> 4x less
//    L2 traffic per MFMA (round-4 was W-refetch L2-BW bound); no branchy prefetch.
//  - SPMM gathers read bf16 shadow tables (128 B/row instead of 256 B); f32 z
//    still written for the final GEMM. Shadows alias the old hraw slot (ws same).
//  - edge_index int64 path uses int2 loads.

typedef __bf16 bf16x8 __attribute__((ext_vector_type(8)));
typedef float  f32x4  __attribute__((ext_vector_type(4)));

#define NN   100000
#define EE   800000
#define IND  512
#define HID  64
#define ZD   320
#define CLS  40
#define NCH  98           // ceil(NN/1024)
#define NWAVE 1563        // ceil(NN/64) waves for embed

static __device__ __forceinline__ float bf2f(unsigned short s) {
  unsigned int u = ((unsigned int)s) << 16;
  return __builtin_bit_cast(float, u);
}
static __device__ __forceinline__ unsigned short f2bf(float f) {
  unsigned int u = __builtin_bit_cast(unsigned int, f);
  u += 0x7FFFu + ((u >> 16) & 1u);   // RNE
  return (unsigned short)(u >> 16);
}
static __device__ __forceinline__ float ldsc(const void* p, int i, int fm) {
  return fm ? ((const float*)p)[i] : bf2f(((const unsigned short*)p)[i]);
}
static __device__ __forceinline__ float i2f(int v) { return __builtin_bit_cast(float, v); }
static __device__ __forceinline__ void split8r(f32x4 u0, f32x4 u1, bf16x8& hi, bf16x8& lo) {
  #pragma unroll
  for (int j = 0; j < 4; ++j) {
    float v0 = u0[j], v1 = u1[j];
    __bf16 h0 = (__bf16)v0, h1 = (__bf16)v1;
    hi[j] = h0;     lo[j] = (__bf16)(v0 - (float)h0);
    hi[4 + j] = h1; lo[4 + j] = (__bf16)(v1 - (float)h1);
  }
}

// ---------------- dtype probe ----------------
__global__ void k_probe(const unsigned short* __restrict__ xs,
                        const int* __restrict__ ei, int* __restrict__ flags) {
  __shared__ int cnt_big, cnt_nz;
  if (threadIdx.x == 0) { cnt_big = 0; cnt_nz = 0; }
  __syncthreads();
  unsigned short u = xs[threadIdx.x];
  int expf = (u >> 7) & 0xFF;
  if (expf >= 0x8D) atomicAdd(&cnt_big, 1);      // |bf16| >= 2^14 (or NaN/Inf)
  if (threadIdx.x < 128 && ei[2 * threadIdx.x + 1] != 0) atomicAdd(&cnt_nz, 1);
  __syncthreads();
  if (threadIdx.x == 0) {
    flags[0] = (cnt_big >= 2) ? 1 : 0;
    flags[1] = (cnt_nz < 64) ? 1 : 0;
  }
}

// ---------------- weight pre-split ----------------
__global__ void k_wsplit(const void* __restrict__ Wv, const int* __restrict__ flags,
                         int n, unsigned short* __restrict__ hi,
                         unsigned short* __restrict__ lo) {
  int i = blockIdx.x * 256 + threadIdx.x;
  if (i >= n) return;
  float v = ldsc(Wv, i, flags[0]);
  __bf16 h = (__bf16)v;
  hi[i] = __builtin_bit_cast(unsigned short, h);
  __bf16 l = (__bf16)(v - (float)h);
  lo[i] = __builtin_bit_cast(unsigned short, l);
}

// ---------------- graph build ----------------
__global__ void k_deg(const int* __restrict__ ei, const int* __restrict__ flags,
                      int* __restrict__ deg) {
  int e = blockIdx.x * 256 + threadIdx.x;
  if (e >= EE) return;
  int r, c;
  if (flags[1]) { r = ((const int2*)ei)[e].x; c = ((const int2*)ei)[EE + e].x; }
  else          { r = ei[e];                  c = ei[EE + e]; }
  if (r != c) { atomicAdd(&deg[r], 1); atomicAdd(&deg[c], 1); }
}

__global__ void k_chunksum(const int* __restrict__ deg, int* __restrict__ csum) {
  __shared__ int sd[1024];
  int i = blockIdx.x * 1024 + threadIdx.x;
  sd[threadIdx.x] = (i < NN) ? deg[i] : 0;
  __syncthreads();
  for (int s = 512; s > 0; s >>= 1) {
    if (threadIdx.x < s) sd[threadIdx.x] += sd[threadIdx.x + s];
    __syncthreads();
  }
  if (threadIdx.x == 0) csum[blockIdx.x] = sd[0];
}

__global__ void k_scanchunks(int* __restrict__ csum, int* __restrict__ total) {
  if (threadIdx.x == 0) {
    int acc = 0;
    for (int i = 0; i < NCH; ++i) { int v = csum[i]; csum[i] = acc; acc += v; }
    total[0] = acc;
  }
}

__global__ void k_offs(const int* __restrict__ deg, const int* __restrict__ cbase,
                       int* __restrict__ offs, float* __restrict__ dinv) {
  __shared__ int sd[1024];
  int i = blockIdx.x * 1024 + threadIdx.x;
  int v = (i < NN) ? deg[i] : 0;
  sd[threadIdx.x] = v;
  __syncthreads();
  for (int s = 1; s < 1024; s <<= 1) {
    int t = (threadIdx.x >= s) ? sd[threadIdx.x - s] : 0;
    __syncthreads();
    sd[threadIdx.x] += t;
    __syncthreads();
  }
  if (i < NN) {
    offs[i] = cbase[blockIdx.x] + sd[threadIdx.x] - v;
    dinv[i] = (v > 0) ? rsqrtf((float)v) : 0.f;
  }
}

__global__ void k_fill(const int* __restrict__ ei, const int* __restrict__ flags,
                       const int* __restrict__ offs,
                       int* __restrict__ fill, const float* __restrict__ dinv,
                       int2* __restrict__ ep) {
  int e = blockIdx.x * 256 + threadIdx.x;
  if (e >= EE) return;
  int r, c;
  if (flags[1]) { r = ((const int2*)ei)[e].x; c = ((const int2*)ei)[EE + e].x; }
  else          { r = ei[e];                  c = ei[EE + e]; }
  if (r == c) return;
  float w = dinv[r] * dinv[c];
  int wb = __builtin_bit_cast(int, w);
  int p = offs[r] + atomicAdd(&fill[r], 1);
  ep[p] = make_int2(c, wb);
  int q = offs[c] + atomicAdd(&fill[c], 1);
  ep[q] = make_int2(r, wb);
}

// ---------------- embed GEMM: hb = bf16(relu(x @ W^T + b)), + BN stats -------
// M=64 per wave: 4 row-tiles share each W hi/lo fragment (4x less L2 traffic).
__global__ __launch_bounds__(256) void k_embed(
    const void* __restrict__ xv,
    const unsigned short* __restrict__ whi, const unsigned short* __restrict__ wlo,
    const void* __restrict__ bEv, const int* __restrict__ flags,
    unsigned short* __restrict__ hb, float* __restrict__ bnsum, float* __restrict__ bnsq) {
  __shared__ float s_sum[64], s_sq[64];
  const int fm = flags[0];
  const int wave = threadIdx.x >> 6, lane = threadIdx.x & 63;
  const int l15 = lane & 15, quad = lane >> 4;
  const int wid = blockIdx.x * 4 + wave;
  const int rb = wid * 64;
  if (threadIdx.x < 64) { s_sum[threadIdx.x] = 0.f; s_sq[threadIdx.x] = 0.f; }
  __syncthreads();
  f32x4 acc[4][4] = {};
  if (wid < NWAVE) {
    if (fm) {
      const float* xr[4];
      #pragma unroll
      for (int t = 0; t < 4; ++t) {
        int row = rb + t * 16 + l15; if (row > NN - 1) row = NN - 1;
        xr[t] = (const float*)xv + (size_t)row * IND + quad * 8;
      }
      for (int ks = 0; ks < 16; ++ks) {
        bf16x8 bhi[4], blo[4];
        #pragma unroll
        for (int nt = 0; nt < 4; ++nt) {
          size_t wb = (size_t)(nt * 16 + l15) * IND + ks * 32 + quad * 8;
          bhi[nt] = *(const bf16x8*)(whi + wb);
          blo[nt] = *(const bf16x8*)(wlo + wb);
        }
        #pragma unroll
        for (int t = 0; t < 4; ++t) {
          f32x4 u0 = *(const f32x4*)(xr[t] + ks * 32);
          f32x4 u1 = *(const f32x4*)(xr[t] + ks * 32 + 4);
          bf16x8 ahi, alo;
          split8r(u0, u1, ahi, alo);
          #pragma unroll
          for (int nt = 0; nt < 4; ++nt) {
            acc[t][nt] = __builtin_amdgcn_mfma_f32_16x16x32_bf16(ahi, bhi[nt], acc[t][nt], 0, 0, 0);
            acc[t][nt] = __builtin_amdgcn_mfma_f32_16x16x32_bf16(alo, bhi[nt], acc[t][nt], 0, 0, 0);
            acc[t][nt] = __builtin_amdgcn_mfma_f32_16x16x32_bf16(ahi, blo[nt], acc[t][nt], 0, 0, 0);
          }
        }
      }
    } else {
      const unsigned short* xr[4];
      #pragma unroll
      for (int t = 0; t < 4; ++t) {
        int row = rb + t * 16 + l15; if (row > NN - 1) row = NN - 1;
        xr[t] = (const unsigned short*)xv + (size_t)row * IND + quad * 8;
      }
      for (int ks = 0; ks < 16; ++ks) {
        bf16x8 bhi[4];
        #pragma unroll
        for (int nt = 0; nt < 4; ++nt)
          bhi[nt] = *(const bf16x8*)(whi + (size_t)(nt * 16 + l15) * IND + ks * 32 + quad * 8);
        #pragma unroll
        for (int t = 0; t < 4; ++t) {
          bf16x8 a = *(const bf16x8*)(xr[t] + ks * 32);
          #pragma unroll
          for (int nt = 0; nt < 4; ++nt)
            acc[t][nt] = __builtin_amdgcn_mfma_f32_16x16x32_bf16(a, bhi[nt], acc[t][nt], 0, 0, 0);
        }
      }
    }
    #pragma unroll
    for (int nt = 0; nt < 4; ++nt) {
      int n = nt * 16 + l15;
      float bb = ldsc(bEv, n, fm);
      float ps = 0.f, pq = 0.f;
      #pragma unroll
      for (int t = 0; t < 4; ++t) {
        #pragma unroll
        for (int r = 0; r < 4; ++r) {
          int row = rb + t * 16 + quad * 4 + r;
          if (row < NN) {
            float v = fmaxf(acc[t][nt][r] + bb, 0.f);
            hb[(size_t)row * 64 + n] = f2bf(v);
            ps += v; pq += v * v;
          }
        }
      }
      ps += __shfl_xor(ps, 16); pq += __shfl_xor(pq, 16);
      ps += __shfl_xor(ps, 32); pq += __shfl_xor(pq, 32);
      if (quad == 0) { atomicAdd(&s_sum[n], ps); atomicAdd(&s_sq[n], pq); }
    }
  }
  __syncthreads();
  if (threadIdx.x < 64) {
    atomicAdd(&bnsum[threadIdx.x], s_sum[threadIdx.x]);
    atomicAdd(&bnsq[threadIdx.x], s_sq[threadIdx.x]);
  }
}

__global__ void k_bnfin(const float* __restrict__ bnsum, const float* __restrict__ bnsq,
                        const void* __restrict__ gv, const void* __restrict__ bv,
                        const int* __restrict__ flags, float* __restrict__ ab) {
  int c = threadIdx.x;
  int fm = flags[0];
  if (c < 64) {
    float mu = bnsum[c] * (1.0f / (float)NN);
    float var = bnsq[c] * (1.0f / (float)NN) - mu * mu;
    float a = ldsc(gv, c, fm) / sqrtf(var + 1e-5f);
    float b = ldsc(bv, c, fm) - mu * a;
    ab[c] = a; ab[64 + c] = b;
  }
}

// ---------------- SPMM kernels: x8 gather of bf16 shadow tables --------------
#define GATHER8(SRC, STRIDE)                                                   \
  float a[8] = {}; float sw = 0, sq = 0; (void)sw; (void)sq;                   \
  int j = s;                                                                   \
  for (; j + 8 <= e; j += 8) {                                                 \
    int2 p[8];                                                                 \
    _Pragma("unroll") for (int t = 0; t < 8; ++t) p[t] = ep[j + t];            \
    float xv[8];                                                               \
    _Pragma("unroll") for (int t = 0; t < 8; ++t)                              \
      xv[t] = bf2f(SRC[(size_t)p[t].x * STRIDE + lane]);                       \
    _Pragma("unroll") for (int t = 0; t < 8; ++t) {                            \
      float w = i2f(p[t].y);                                                   \
      a[t] = fmaf(w, xv[t], a[t]); sw += w; sq = fmaf(w, w, sq);               \
    }                                                                          \
  }                                                                            \
  for (; j < e; ++j) {                                                         \
    int2 p = ep[j]; float w = i2f(p.y);                                        \
    a[0] = fmaf(w, bf2f(SRC[(size_t)p.x * STRIDE + lane]), a[0]);              \
    sw += w; sq = fmaf(w, w, sq);                                              \
  }                                                                            \
  float acc = ((a[0] + a[1]) + (a[2] + a[3])) + ((a[4] + a[5]) + (a[6] + a[7]));

// SPMM1: gather hb; z0 = BN(hb[r]); h1 = a*Sum(w*hb)+b*Sum(w); diag2 = Sum(w^2)
__global__ __launch_bounds__(256) void k_sp1(
    const int* __restrict__ offs, const int2* __restrict__ ep,
    const unsigned short* __restrict__ hb, const float* __restrict__ bnab,
    float* __restrict__ diag2, float* __restrict__ z,
    unsigned short* __restrict__ h1b) {
  const int r = blockIdx.x * 4 + (threadIdx.x >> 6);
  const int lane = threadIdx.x & 63;
  if (r >= NN) return;
  int s = offs[r], e = offs[r + 1];
  GATHER8(hb, 64)
  float ga = bnab[lane], gb = bnab[64 + lane];
  size_t zr = (size_t)r * ZD;
  z[zr + lane] = fmaf(ga, bf2f(hb[(size_t)r * 64 + lane]), gb);
  float h1 = ga * acc + gb * sw;
  z[zr + 64 + lane] = h1;
  h1b[(size_t)r * 64 + lane] = f2bf(h1);
  if (lane == 0) diag2[r] = sq;
}

// SPMM2: gather h1b; h2 = acc - diag2*z0; write z2; curb = bf16(h1 + h2)
__global__ __launch_bounds__(256) void k_sp2(
    const int* __restrict__ offs, const int2* __restrict__ ep,
    const unsigned short* __restrict__ h1b, const float* __restrict__ diag2,
    float* __restrict__ z, unsigned short* __restrict__ curb) {
  const int r = blockIdx.x * 4 + (threadIdx.x >> 6);
  const int lane = threadIdx.x & 63;
  if (r >= NN) return;
  int s = offs[r], e = offs[r + 1];
  GATHER8(h1b, 64)
  size_t zr = (size_t)r * ZD;
  float h2 = acc - diag2[r] * z[zr + lane];
  z[zr + 128 + lane] = h2;
  curb[(size_t)r * 64 + lane] = f2bf(z[zr + 64 + lane] + h2);
}

// SPMM3/4 generic: gather xin16; y = acc [- diag2*bf(corrb)]; z[.,zoff]=y [,outb]
__global__ __launch_bounds__(256) void k_spg(
    const int* __restrict__ offs, const int2* __restrict__ ep,
    const unsigned short* __restrict__ xin, const float* __restrict__ diag2,
    const unsigned short* __restrict__ corrb,
    float* __restrict__ z, long zoff, unsigned short* __restrict__ outb) {
  const int r = blockIdx.x * 4 + (threadIdx.x >> 6);
  const int lane = threadIdx.x & 63;
  if (r >= NN) return;
  int s = offs[r], e = offs[r + 1];
  GATHER8(xin, 64)
  if (corrb) acc -= diag2[r] * bf2f(corrb[(size_t)r * 64 + lane]);
  z[(size_t)r * ZD + zoff + lane] = acc;
  if (outb) outb[(size_t)r * 64 + lane] = f2bf(acc);
}

// ---------------- final: out = relu(z @ W1^T + b1) @ W2^T + b2 ----------------
__global__ __launch_bounds__(256) void k_final(
    const float* __restrict__ z,
    const unsigned short* __restrict__ w1hi, const unsigned short* __restrict__ w1lo,
    const void* __restrict__ b1v,
    const unsigned short* __restrict__ w2hi, const unsigned short* __restrict__ w2lo,
    const void* __restrict__ b2v,
    const int* __restrict__ flags, void* __restrict__ outv) {
  __shared__ float tls[4][16][68];
  const int fm = flags[0];
  const int wave = threadIdx.x >> 6, lane = threadIdx.x & 63;
  const int l15 = lane & 15, quad = lane >> 4;
  const int gid = blockIdx.x * 4 + wave;
  const bool valid = gid < (NN + 15) / 16;
  if (valid) {
    const int rb = gid * 16;
    f32x4 acc[4] = {};
    const float* zr = z + (size_t)(rb + l15) * ZD + quad * 8;
    for (int ks = 0; ks < 10; ++ks) {
      f32x4 u0 = *(const f32x4*)(zr + ks * 32);
      f32x4 u1 = *(const f32x4*)(zr + ks * 32 + 4);
      bf16x8 ahi, alo;
      split8r(u0, u1, ahi, alo);
      #pragma unroll
      for (int nt = 0; nt < 4; ++nt) {
        size_t wb = (size_t)(nt * 16 + l15) * ZD + ks * 32 + quad * 8;
        bf16x8 bhi = *(const bf16x8*)(w1hi + wb);
        bf16x8 blo = *(const bf16x8*)(w1lo + wb);
        acc[nt] = __builtin_amdgcn_mfma_f32_16x16x32_bf16(ahi, bhi, acc[nt], 0, 0, 0);
        acc[nt] = __builtin_amdgcn_mfma_f32_16x16x32_bf16(alo, bhi, acc[nt], 0, 0, 0);
        acc[nt] = __builtin_amdgcn_mfma_f32_16x16x32_bf16(ahi, blo, acc[nt], 0, 0, 0);
      }
    }
    #pragma unroll
    for (int nt = 0; nt < 4; ++nt) {
      int n = nt * 16 + l15;
      float bb = ldsc(b1v, n, fm);
      #pragma unroll
      for (int r = 0; r < 4; ++r)
        tls[wave][quad * 4 + r][n] = fmaxf(acc[nt][r] + bb, 0.f);
    }
  }
  __syncthreads();
  if (valid) {
    const int rb = gid * 16;
    f32x4 acc2[3] = {};
    #pragma unroll
    for (int ks = 0; ks < 2; ++ks) {
      bf16x8 ahi, alo;
      #pragma unroll
      for (int j = 0; j < 8; ++j) {
        float v = tls[wave][l15][ks * 32 + quad * 8 + j];
        __bf16 h = (__bf16)v;
        ahi[j] = h; alo[j] = (__bf16)(v - (float)h);
      }
      #pragma unroll
      for (int nt = 0; nt < 3; ++nt) {
        int n = nt * 16 + l15;
        bf16x8 bhi = {}, blo = {};
        if (n < CLS) {
          size_t wb = (size_t)n * HID + ks * 32 + quad * 8;
          bhi = *(const bf16x8*)(w2hi + wb);
          blo = *(const bf16x8*)(w2lo + wb);
        }
        acc2[nt] = __builtin_amdgcn_mfma_f32_16x16x32_bf16(ahi, bhi, acc2[nt], 0, 0, 0);
        acc2[nt] = __builtin_amdgcn_mfma_f32_16x16x32_bf16(alo, bhi, acc2[nt], 0, 0, 0);
        acc2[nt] = __builtin_amdgcn_mfma_f32_16x16x32_bf16(ahi, blo, acc2[nt], 0, 0, 0);
      }
    }
    #pragma unroll
    for (int nt = 0; nt < 3; ++nt) {
      int n = nt * 16 + l15;
      if (n < CLS) {
        float bb = ldsc(b2v, n, fm);
        #pragma unroll
        for (int r = 0; r < 4; ++r) {
          float v = acc2[nt][r] + bb;
          size_t oi = (size_t)(rb + quad * 4 + r) * CLS + n;
          if (fm) ((float*)outv)[oi] = v;
          else    ((unsigned short*)outv)[oi] = f2bf(v);
        }
      }
    }
  }
}

extern "C" void kernel_launch(void* const* d_in, const int* in_sizes, int n_in,
                              void* d_out, int out_size, void* d_ws, size_t ws_size,
                              hipStream_t stream) {
  (void)in_sizes; (void)n_in; (void)out_size; (void)ws_size;
  const void* x   = d_in[0];
  const int*  ei  = (const int*)d_in[1];
  const void* WE  = d_in[2];
  const void* bE  = d_in[3];
  const void* gam = d_in[4];
  const void* bet = d_in[5];
  const void* W1  = d_in[6];
  const void* b1  = d_in[7];
  const void* W2  = d_in[8];
  const void* b2  = d_in[9];

  float* wsf = (float*)d_ws;
  int*   wsi = (int*)d_ws;
  // word-offset layout; total ~168.6 MB (same as round 4)
  int*   deg   = wsi + 0;          // NN (zeroed)
  int*   fill  = wsi + 100000;     // NN (zeroed)
  float* bnsum = wsf + 200000;     // 64 (zeroed)
  float* bnsq  = wsf + 200064;     // 64 (zeroed)
  int*   flags = wsi + 200128;     // 8
  float* bnab  = wsf + 200136;     // 128
  float* dinv  = wsf + 200264;     // NN
  int*   offs  = wsi + 300264;     // NN+1
  int*   cbase = wsi + 400272;     // NCH (pad to 400384)
  unsigned short* whi  = (unsigned short*)(wsi + 400384);  // 64*512
  unsigned short* wlo  = (unsigned short*)(wsi + 416768);
  unsigned short* w1hi = (unsigned short*)(wsi + 433152);  // 64*320
  unsigned short* w1lo = (unsigned short*)(wsi + 443392);
  unsigned short* w2hi = (unsigned short*)(wsi + 453632);  // 40*64
  unsigned short* w2lo = (unsigned short*)(wsi + 454912);
  int2*  ep    = (int2*)(wsi + 456192);   // 1.6M edges
  float* diag2 = wsf + 3656192;    // NN
  // bf16 shadow slots (each NN*64 ushort = 3.2M words), in old hraw footprint:
  unsigned short* S1 = (unsigned short*)(wsi + 3756192);   // hb, later curb
  unsigned short* S2 = (unsigned short*)(wsi + 6956192);   // h1b, later h3b
  float* z     = wsf + 10156192;   // NN*ZD

  hipMemsetAsync(d_ws, 0, (size_t)200128 * 4, stream);

  k_probe     <<<1, 256, 0, stream>>>((const unsigned short*)x, ei, flags);
  k_wsplit    <<<(64 * IND + 255) / 256, 256, 0, stream>>>(WE, flags, 64 * IND, whi, wlo);
  k_wsplit    <<<(64 * ZD + 255) / 256, 256, 0, stream>>>(W1, flags, 64 * ZD, w1hi, w1lo);
  k_wsplit    <<<(CLS * HID + 255) / 256, 256, 0, stream>>>(W2, flags, CLS * HID, w2hi, w2lo);

  k_deg       <<<EE / 256, 256, 0, stream>>>(ei, flags, deg);
  k_chunksum  <<<NCH, 1024, 0, stream>>>(deg, cbase);
  k_scanchunks<<<1, 64, 0, stream>>>(cbase, offs + NN);
  k_offs      <<<NCH, 1024, 0, stream>>>(deg, cbase, offs, dinv);
  k_fill      <<<EE / 256, 256, 0, stream>>>(ei, flags, offs, fill, dinv, ep);

  k_embed     <<<(NWAVE + 3) / 4, 256, 0, stream>>>(x, whi, wlo, bE, flags, S1, bnsum, bnsq);
  k_bnfin     <<<1, 64, 0, stream>>>(bnsum, bnsq, gam, bet, flags, bnab);

  k_sp1<<<NN / 4, 256, 0, stream>>>(offs, ep, S1, bnab, diag2, z, S2);         // hb->h1
  k_sp2<<<NN / 4, 256, 0, stream>>>(offs, ep, S2, diag2, z, S1);               // h1b->h2, curb=S1
  k_spg<<<NN / 4, 256, 0, stream>>>(offs, ep, S1, diag2, nullptr, z, 192, S2); // cur->h3, h3b=S2
  k_spg<<<NN / 4, 256, 0, stream>>>(offs, ep, S2, diag2, S1, z, 256, nullptr); // h3->h4

  k_final<<<((NN + 15) / 16 + 3) / 4, 256, 0, stream>>>(z, w1hi, w1lo, b1,
                                                        w2hi, w2lo, b2, flags, d_out);
}

// Round 6
// 864.851 us; speedup vs baseline: 1.0479x; 1.0009x over previous
//
#include <hip/hip_runtime.h>
#include <stdint.h>

// H2GCN forward on MI355X (gfx950). Round 6:
//  - k_embed: 2-wave K-split blocks (K=256/wave, LDS reduce) -> 3126 waves
//    (3/SIMD) instead of 1563 (1.5/SIMD): grid was the occupancy limiter.
//  - z stored as bf16 hi/lo planes: SPMM writes ARE the pre-split MFMA
//    A-operands for k_final (no split VALU there) and the gather tables.
//  - k_final: M=32/wave (3125 waves), direct hi/lo A-frag loads.

typedef __bf16 bf16x8 __attribute__((ext_vector_type(8)));
typedef float  f32x4  __attribute__((ext_vector_type(4)));

#define NN   100000
#define EE   800000
#define IND  512
#define HID  64
#define ZD   320
#define CLS  40
#define NCH  98           // ceil(NN/1024)
#define NBLK 1563         // ceil(NN/64) embed blocks

static __device__ __forceinline__ float bf2f(unsigned short s) {
  unsigned int u = ((unsigned int)s) << 16;
  return __builtin_bit_cast(float, u);
}
static __device__ __forceinline__ unsigned short f2bf(float f) {
  unsigned int u = __builtin_bit_cast(unsigned int, f);
  u += 0x7FFFu + ((u >> 16) & 1u);   // RNE
  return (unsigned short)(u >> 16);
}
static __device__ __forceinline__ float ldsc(const void* p, int i, int fm) {
  return fm ? ((const float*)p)[i] : bf2f(((const unsigned short*)p)[i]);
}
static __device__ __forceinline__ float i2f(int v) { return __builtin_bit_cast(float, v); }
static __device__ __forceinline__ void split8r(f32x4 u0, f32x4 u1, bf16x8& hi, bf16x8& lo) {
  #pragma unroll
  for (int j = 0; j < 4; ++j) {
    float v0 = u0[j], v1 = u1[j];
    __bf16 h0 = (__bf16)v0, h1 = (__bf16)v1;
    hi[j] = h0;     lo[j] = (__bf16)(v0 - (float)h0);
    hi[4 + j] = h1; lo[4 + j] = (__bf16)(v1 - (float)h1);
  }
}
static __device__ __forceinline__ void splitsc(float v, unsigned short* hp, unsigned short* lp) {
  __bf16 h = (__bf16)v;
  *hp = __builtin_bit_cast(unsigned short, h);
  __bf16 l = (__bf16)(v - (float)h);
  *lp = __builtin_bit_cast(unsigned short, l);
}

// ---------------- dtype probe ----------------
__global__ void k_probe(const unsigned short* __restrict__ xs,
                        const int* __restrict__ ei, int* __restrict__ flags) {
  __shared__ int cnt_big, cnt_nz;
  if (threadIdx.x == 0) { cnt_big = 0; cnt_nz = 0; }
  __syncthreads();
  unsigned short u = xs[threadIdx.x];
  int expf = (u >> 7) & 0xFF;
  if (expf >= 0x8D) atomicAdd(&cnt_big, 1);
  if (threadIdx.x < 128 && ei[2 * threadIdx.x + 1] != 0) atomicAdd(&cnt_nz, 1);
  __syncthreads();
  if (threadIdx.x == 0) {
    flags[0] = (cnt_big >= 2) ? 1 : 0;
    flags[1] = (cnt_nz < 64) ? 1 : 0;
  }
}

// ---------------- weight pre-split ----------------
__global__ void k_wsplit(const void* __restrict__ Wv, const int* __restrict__ flags,
                         int n, unsigned short* __restrict__ hi,
                         unsigned short* __restrict__ lo) {
  int i = blockIdx.x * 256 + threadIdx.x;
  if (i >= n) return;
  float v = ldsc(Wv, i, flags[0]);
  splitsc(v, hi + i, lo + i);
}

// ---------------- graph build ----------------
__global__ void k_deg(const int* __restrict__ ei, const int* __restrict__ flags,
                      int* __restrict__ deg) {
  int e = blockIdx.x * 256 + threadIdx.x;
  if (e >= EE) return;
  int r, c;
  if (flags[1]) { r = ((const int2*)ei)[e].x; c = ((const int2*)ei)[EE + e].x; }
  else          { r = ei[e];                  c = ei[EE + e]; }
  if (r != c) { atomicAdd(&deg[r], 1); atomicAdd(&deg[c], 1); }
}

__global__ void k_chunksum(const int* __restrict__ deg, int* __restrict__ csum) {
  __shared__ int sd[1024];
  int i = blockIdx.x * 1024 + threadIdx.x;
  sd[threadIdx.x] = (i < NN) ? deg[i] : 0;
  __syncthreads();
  for (int s = 512; s > 0; s >>= 1) {
    if (threadIdx.x < s) sd[threadIdx.x] += sd[threadIdx.x + s];
    __syncthreads();
  }
  if (threadIdx.x == 0) csum[blockIdx.x] = sd[0];
}

__global__ void k_scanchunks(int* __restrict__ csum, int* __restrict__ total) {
  if (threadIdx.x == 0) {
    int acc = 0;
    for (int i = 0; i < NCH; ++i) { int v = csum[i]; csum[i] = acc; acc += v; }
    total[0] = acc;
  }
}

__global__ void k_offs(const int* __restrict__ deg, const int* __restrict__ cbase,
                       int* __restrict__ offs, float* __restrict__ dinv) {
  __shared__ int sd[1024];
  int i = blockIdx.x * 1024 + threadIdx.x;
  int v = (i < NN) ? deg[i] : 0;
  sd[threadIdx.x] = v;
  __syncthreads();
  for (int s = 1; s < 1024; s <<= 1) {
    int t = (threadIdx.x >= s) ? sd[threadIdx.x - s] : 0;
    __syncthreads();
    sd[threadIdx.x] += t;
    __syncthreads();
  }
  if (i < NN) {
    offs[i] = cbase[blockIdx.x] + sd[threadIdx.x] - v;
    dinv[i] = (v > 0) ? rsqrtf((float)v) : 0.f;
  }
}

__global__ void k_fill(const int* __restrict__ ei, const int* __restrict__ flags,
                       const int* __restrict__ offs,
                       int* __restrict__ fill, const float* __restrict__ dinv,
                       int2* __restrict__ ep) {
  int e = blockIdx.x * 256 + threadIdx.x;
  if (e >= EE) return;
  int r, c;
  if (flags[1]) { r = ((const int2*)ei)[e].x; c = ((const int2*)ei)[EE + e].x; }
  else          { r = ei[e];                  c = ei[EE + e]; }
  if (r == c) return;
  float w = dinv[r] * dinv[c];
  int wb = __builtin_bit_cast(int, w);
  int p = offs[r] + atomicAdd(&fill[r], 1);
  ep[p] = make_int2(c, wb);
  int q = offs[c] + atomicAdd(&fill[c], 1);
  ep[q] = make_int2(r, wb);
}

// ---------------- embed GEMM: hb = bf16(relu(x @ W^T + b)), + BN stats -------
// Block = 128 threads = 2 waves; wave w computes K slice [w*256,(w+1)*256).
// Wave1 dumps acc to LDS; wave0 reduces, applies bias/relu, writes hb + BN.
__global__ __launch_bounds__(128) void k_embed(
    const void* __restrict__ xv,
    const unsigned short* __restrict__ whi, const unsigned short* __restrict__ wlo,
    const void* __restrict__ bEv, const int* __restrict__ flags,
    unsigned short* __restrict__ hb, float* __restrict__ bnsum, float* __restrict__ bnsq) {
  __shared__ float sacc[64][65];
  const int fm = flags[0];
  const int wave = threadIdx.x >> 6, lane = threadIdx.x & 63;
  const int l15 = lane & 15, quad = lane >> 4;
  const int rb = blockIdx.x * 64;
  f32x4 acc[4][4] = {};
  if (fm) {
    const float* xr[4];
    #pragma unroll
    for (int t = 0; t < 4; ++t) {
      int row = rb + t * 16 + l15; if (row > NN - 1) row = NN - 1;
      xr[t] = (const float*)xv + (size_t)row * IND + quad * 8;
    }
    for (int ks = 0; ks < 8; ++ks) {
      const int kk = wave * 8 + ks;
      bf16x8 bhi[4], blo[4];
      #pragma unroll
      for (int nt = 0; nt < 4; ++nt) {
        size_t wb = (size_t)(nt * 16 + l15) * IND + kk * 32 + quad * 8;
        bhi[nt] = *(const bf16x8*)(whi + wb);
        blo[nt] = *(const bf16x8*)(wlo + wb);
      }
      #pragma unroll
      for (int t = 0; t < 4; ++t) {
        f32x4 u0 = *(const f32x4*)(xr[t] + kk * 32);
        f32x4 u1 = *(const f32x4*)(xr[t] + kk * 32 + 4);
        bf16x8 ahi, alo;
        split8r(u0, u1, ahi, alo);
        #pragma unroll
        for (int nt = 0; nt < 4; ++nt) {
          acc[t][nt] = __builtin_amdgcn_mfma_f32_16x16x32_bf16(ahi, bhi[nt], acc[t][nt], 0, 0, 0);
          acc[t][nt] = __builtin_amdgcn_mfma_f32_16x16x32_bf16(alo, bhi[nt], acc[t][nt], 0, 0, 0);
          acc[t][nt] = __builtin_amdgcn_mfma_f32_16x16x32_bf16(ahi, blo[nt], acc[t][nt], 0, 0, 0);
        }
      }
    }
  } else {
    const unsigned short* xr[4];
    #pragma unroll
    for (int t = 0; t < 4; ++t) {
      int row = rb + t * 16 + l15; if (row > NN - 1) row = NN - 1;
      xr[t] = (const unsigned short*)xv + (size_t)row * IND + quad * 8;
    }
    for (int ks = 0; ks < 8; ++ks) {
      const int kk = wave * 8 + ks;
      bf16x8 bhi[4];
      #pragma unroll
      for (int nt = 0; nt < 4; ++nt)
        bhi[nt] = *(const bf16x8*)(whi + (size_t)(nt * 16 + l15) * IND + kk * 32 + quad * 8);
      #pragma unroll
      for (int t = 0; t < 4; ++t) {
        bf16x8 a = *(const bf16x8*)(xr[t] + kk * 32);
        #pragma unroll
        for (int nt = 0; nt < 4; ++nt)
          acc[t][nt] = __builtin_amdgcn_mfma_f32_16x16x32_bf16(a, bhi[nt], acc[t][nt], 0, 0, 0);
      }
    }
  }
  if (wave == 1) {
    #pragma unroll
    for (int nt = 0; nt < 4; ++nt)
      #pragma unroll
      for (int t = 0; t < 4; ++t)
        #pragma unroll
        for (int r = 0; r < 4; ++r)
          sacc[t * 16 + quad * 4 + r][nt * 16 + l15] = acc[t][nt][r];
  }
  __syncthreads();
  if (wave == 0) {
    #pragma unroll
    for (int nt = 0; nt < 4; ++nt) {
      int n = nt * 16 + l15;
      float bb = ldsc(bEv, n, fm);
      float ps = 0.f, pq = 0.f;
      #pragma unroll
      for (int t = 0; t < 4; ++t) {
        #pragma unroll
        for (int r = 0; r < 4; ++r) {
          int row = rb + t * 16 + quad * 4 + r;
          if (row < NN) {
            float v = acc[t][nt][r] + sacc[t * 16 + quad * 4 + r][n] + bb;
            v = fmaxf(v, 0.f);
            hb[(size_t)row * 64 + n] = f2bf(v);
            ps += v; pq += v * v;
          }
        }
      }
      ps += __shfl_xor(ps, 16); pq += __shfl_xor(pq, 16);
      ps += __shfl_xor(ps, 32); pq += __shfl_xor(pq, 32);
      if (quad == 0) { atomicAdd(&bnsum[n], ps); atomicAdd(&bnsq[n], pq); }
    }
  }
}

__global__ void k_bnfin(const float* __restrict__ bnsum, const float* __restrict__ bnsq,
                        const void* __restrict__ gv, const void* __restrict__ bv,
                        const int* __restrict__ flags, float* __restrict__ ab) {
  int c = threadIdx.x;
  int fm = flags[0];
  if (c < 64) {
    float mu = bnsum[c] * (1.0f / (float)NN);
    float var = bnsq[c] * (1.0f / (float)NN) - mu * mu;
    float a = ldsc(gv, c, fm) / sqrtf(var + 1e-5f);
    float b = ldsc(bv, c, fm) - mu * a;
    ab[c] = a; ab[64 + c] = b;
  }
}

// ---------------- SPMM: x8 gather of bf16 tables ----------------
#define GATHER8(SRC, STRIDE)                                                   \
  float a[8] = {}; float sw = 0, sq = 0; (void)sw; (void)sq;                   \
  int j = s;                                                                   \
  for (; j + 8 <= e; j += 8) {                                                 \
    int2 p[8];                                                                 \
    _Pragma("unroll") for (int t = 0; t < 8; ++t) p[t] = ep[j + t];            \
    float xv[8];                                                               \
    _Pragma("unroll") for (int t = 0; t < 8; ++t)                              \
      xv[t] = bf2f(SRC[(size_t)p[t].x * STRIDE + lane]);                       \
    _Pragma("unroll") for (int t = 0; t < 8; ++t) {                            \
      float w = i2f(p[t].y);                                                   \
      a[t] = fmaf(w, xv[t], a[t]); sw += w; sq = fmaf(w, w, sq);               \
    }                                                                          \
  }                                                                            \
  for (; j < e; ++j) {                                                         \
    int2 p = ep[j]; float w = i2f(p.y);                                        \
    a[0] = fmaf(w, bf2f(SRC[(size_t)p.x * STRIDE + lane]), a[0]);              \
    sw += w; sq = fmaf(w, w, sq);                                              \
  }                                                                            \
  float acc = ((a[0] + a[1]) + (a[2] + a[3])) + ((a[4] + a[5]) + (a[6] + a[7]));

// SPMM1: gather hb; block0 = BN(hb[r]); block1 = h1; diag2 = Sum(w^2)
__global__ __launch_bounds__(256) void k_sp1(
    const int* __restrict__ offs, const int2* __restrict__ ep,
    const unsigned short* __restrict__ hb, const float* __restrict__ bnab,
    float* __restrict__ diag2,
    unsigned short* __restrict__ zhi, unsigned short* __restrict__ zlo) {
  const int r = blockIdx.x * 4 + (threadIdx.x >> 6);
  const int lane = threadIdx.x & 63;
  if (r >= NN) return;
  int s = offs[r], e = offs[r + 1];
  GATHER8(hb, 64)
  float ga = bnab[lane], gb = bnab[64 + lane];
  size_t zr = (size_t)r * ZD;
  float z0 = fmaf(ga, bf2f(hb[(size_t)r * 64 + lane]), gb);
  float h1 = ga * acc + gb * sw;
  splitsc(z0, zhi + zr + lane, zlo + zr + lane);
  splitsc(h1, zhi + zr + 64 + lane, zlo + zr + 64 + lane);
  if (lane == 0) diag2[r] = sq;
}

// SPMM2: gather block1; h2 = acc - diag2*z0; block2 = h2; curb = bf16(h1+h2)
__global__ __launch_bounds__(256) void k_sp2(
    const int* __restrict__ offs, const int2* __restrict__ ep,
    const float* __restrict__ diag2,
    unsigned short* __restrict__ zhi, unsigned short* __restrict__ zlo,
    unsigned short* __restrict__ curb) {
  const int r = blockIdx.x * 4 + (threadIdx.x >> 6);
  const int lane = threadIdx.x & 63;
  if (r >= NN) return;
  int s = offs[r], e = offs[r + 1];
  const unsigned short* src = zhi + 64;
  GATHER8(src, ZD)
  size_t zr = (size_t)r * ZD;
  float z0 = bf2f(zhi[zr + lane]) + bf2f(zlo[zr + lane]);
  float h1 = bf2f(zhi[zr + 64 + lane]) + bf2f(zlo[zr + 64 + lane]);
  float h2 = acc - diag2[r] * z0;
  splitsc(h2, zhi + zr + 128 + lane, zlo + zr + 128 + lane);
  curb[(size_t)r * 64 + lane] = f2bf(h1 + h2);
}

// SPMM3/4: gather src (stride ss); y = acc [- diag2*bf(corrb)]; block zoff = y
__global__ __launch_bounds__(256) void k_spg(
    const int* __restrict__ offs, const int2* __restrict__ ep,
    const unsigned short* __restrict__ src, long ss,
    const float* __restrict__ diag2, const unsigned short* __restrict__ corrb,
    unsigned short* __restrict__ zhi, unsigned short* __restrict__ zlo, long zoff) {
  const int r = blockIdx.x * 4 + (threadIdx.x >> 6);
  const int lane = threadIdx.x & 63;
  if (r >= NN) return;
  int s = offs[r], e = offs[r + 1];
  GATHER8(src, ss)
  if (corrb) acc -= diag2[r] * bf2f(corrb[(size_t)r * 64 + lane]);
  size_t zi = (size_t)r * ZD + zoff + lane;
  splitsc(acc, zhi + zi, zlo + zi);
}

// ---------------- final: out = relu(z @ W1^T + b1) @ W2^T + b2 ----------------
// M=32/wave; A-frags loaded directly from pre-split zhi/zlo (no VALU split).
__global__ __launch_bounds__(256) void k_final(
    const unsigned short* __restrict__ zhi, const unsigned short* __restrict__ zlo,
    const unsigned short* __restrict__ w1hi, const unsigned short* __restrict__ w1lo,
    const void* __restrict__ b1v,
    const unsigned short* __restrict__ w2hi, const unsigned short* __restrict__ w2lo,
    const void* __restrict__ b2v,
    const int* __restrict__ flags, void* __restrict__ outv) {
  __shared__ float tls[4][2][16][68];
  const int fm = flags[0];
  const int wave = threadIdx.x >> 6, lane = threadIdx.x & 63;
  const int l15 = lane & 15, quad = lane >> 4;
  const int gid = blockIdx.x * 4 + wave;      // 0..3124 valid (32 rows each)
  const bool valid = gid < NN / 32;
  if (valid) {
    const int rb = gid * 32;
    f32x4 acc[2][4] = {};
    size_t zb[2];
    #pragma unroll
    for (int t = 0; t < 2; ++t)
      zb[t] = (size_t)(rb + t * 16 + l15) * ZD + quad * 8;
    for (int ks = 0; ks < 10; ++ks) {
      bf16x8 ahi[2], alo[2];
      #pragma unroll
      for (int t = 0; t < 2; ++t) {
        ahi[t] = *(const bf16x8*)(zhi + zb[t] + ks * 32);
        alo[t] = *(const bf16x8*)(zlo + zb[t] + ks * 32);
      }
      #pragma unroll
      for (int nt = 0; nt < 4; ++nt) {
        size_t wb = (size_t)(nt * 16 + l15) * ZD + ks * 32 + quad * 8;
        bf16x8 bhi = *(const bf16x8*)(w1hi + wb);
        bf16x8 blo = *(const bf16x8*)(w1lo + wb);
        #pragma unroll
        for (int t = 0; t < 2; ++t) {
          acc[t][nt] = __builtin_amdgcn_mfma_f32_16x16x32_bf16(ahi[t], bhi, acc[t][nt], 0, 0, 0);
          acc[t][nt] = __builtin_amdgcn_mfma_f32_16x16x32_bf16(alo[t], bhi, acc[t][nt], 0, 0, 0);
          acc[t][nt] = __builtin_amdgcn_mfma_f32_16x16x32_bf16(ahi[t], blo, acc[t][nt], 0, 0, 0);
        }
      }
    }
    #pragma unroll
    for (int nt = 0; nt < 4; ++nt) {
      int n = nt * 16 + l15;
      float bb = ldsc(b1v, n, fm);
      #pragma unroll
      for (int t = 0; t < 2; ++t)
        #pragma unroll
        for (int r = 0; r < 4; ++r)
          tls[wave][t][quad * 4 + r][n] = fmaxf(acc[t][nt][r] + bb, 0.f);
    }
  }
  __syncthreads();
  if (valid) {
    const int rb = gid * 32;
    f32x4 acc2[2][3] = {};
    #pragma unroll
    for (int ks = 0; ks < 2; ++ks) {
      bf16x8 ahi[2], alo[2];
      #pragma unroll
      for (int t = 0; t < 2; ++t)
        #pragma unroll
        for (int j = 0; j < 8; ++j) {
          float v = tls[wave][t][l15][ks * 32 + quad * 8 + j];
          __bf16 h = (__bf16)v;
          ahi[t][j] = h; alo[t][j] = (__bf16)(v - (float)h);
        }
      #pragma unroll
      for (int nt = 0; nt < 3; ++nt) {
        int n = nt * 16 + l15;
        bf16x8 bhi = {}, blo = {};
        if (n < CLS) {
          size_t wb = (size_t)n * HID + ks * 32 + quad * 8;
          bhi = *(const bf16x8*)(w2hi + wb);
          blo = *(const bf16x8*)(w2lo + wb);
        }
        #pragma unroll
        for (int t = 0; t < 2; ++t) {
          acc2[t][nt] = __builtin_amdgcn_mfma_f32_16x16x32_bf16(ahi[t], bhi, acc2[t][nt], 0, 0, 0);
          acc2[t][nt] = __builtin_amdgcn_mfma_f32_16x16x32_bf16(alo[t], bhi, acc2[t][nt], 0, 0, 0);
          acc2[t][nt] = __builtin_amdgcn_mfma_f32_16x16x32_bf16(ahi[t], blo, acc2[t][nt], 0, 0, 0);
        }
      }
    }
    #pragma unroll
    for (int nt = 0; nt < 3; ++nt) {
      int n = nt * 16 + l15;
      if (n < CLS) {
        float bb = ldsc(b2v, n, fm);
        #pragma unroll
        for (int t = 0; t < 2; ++t)
          #pragma unroll
          for (int r = 0; r < 4; ++r) {
            float v = acc2[t][nt][r] + bb;
            size_t oi = (size_t)(rb + t * 16 + quad * 4 + r) * CLS + n;
            if (fm) ((float*)outv)[oi] = v;
            else    ((unsigned short*)outv)[oi] = f2bf(v);
          }
      }
    }
  }
}

extern "C" void kernel_launch(void* const* d_in, const int* in_sizes, int n_in,
                              void* d_out, int out_size, void* d_ws, size_t ws_size,
                              hipStream_t stream) {
  (void)in_sizes; (void)n_in; (void)out_size; (void)ws_size;
  const void* x   = d_in[0];
  const int*  ei  = (const int*)d_in[1];
  const void* WE  = d_in[2];
  const void* bE  = d_in[3];
  const void* gam = d_in[4];
  const void* bet = d_in[5];
  const void* W1  = d_in[6];
  const void* b1  = d_in[7];
  const void* W2  = d_in[8];
  const void* b2  = d_in[9];

  float* wsf = (float*)d_ws;
  int*   wsi = (int*)d_ws;
  // word-offset layout; total ~168.6 MB (same as round 5)
  int*   deg   = wsi + 0;          // NN (zeroed)
  int*   fill  = wsi + 100000;     // NN (zeroed)
  float* bnsum = wsf + 200000;     // 64 (zeroed)
  float* bnsq  = wsf + 200064;     // 64 (zeroed)
  int*   flags = wsi + 200128;     // 8
  float* bnab  = wsf + 200136;     // 128
  float* dinv  = wsf + 200264;     // NN
  int*   offs  = wsi + 300264;     // NN+1
  int*   cbase = wsi + 400272;     // NCH (pad to 400384)
  unsigned short* whi  = (unsigned short*)(wsi + 400384);  // 64*512
  unsigned short* wlo  = (unsigned short*)(wsi + 416768);
  unsigned short* w1hi = (unsigned short*)(wsi + 433152);  // 64*320
  unsigned short* w1lo = (unsigned short*)(wsi + 443392);
  unsigned short* w2hi = (unsigned short*)(wsi + 453632);  // 40*64
  unsigned short* w2lo = (unsigned short*)(wsi + 454912);
  int2*  ep    = (int2*)(wsi + 456192);   // 1.6M edges
  float* diag2 = wsf + 3656192;    // NN
  unsigned short* hb   = (unsigned short*)(wsi + 3756192);  // NN*64 bf16
  unsigned short* curb = (unsigned short*)(wsi + 6956192);  // NN*64 bf16
  unsigned short* zhi  = (unsigned short*)(wsi + 10156192); // NN*320 bf16
  unsigned short* zlo  = (unsigned short*)(wsi + 26156192); // NN*320 bf16

  hipMemsetAsync(d_ws, 0, (size_t)200128 * 4, stream);

  k_probe     <<<1, 256, 0, stream>>>((const unsigned short*)x, ei, flags);
  k_wsplit    <<<(64 * IND + 255) / 256, 256, 0, stream>>>(WE, flags, 64 * IND, whi, wlo);
  k_wsplit    <<<(64 * ZD + 255) / 256, 256, 0, stream>>>(W1, flags, 64 * ZD, w1hi, w1lo);
  k_wsplit    <<<(CLS * HID + 255) / 256, 256, 0, stream>>>(W2, flags, CLS * HID, w2hi, w2lo);

  k_deg       <<<EE / 256, 256, 0, stream>>>(ei, flags, deg);
  k_chunksum  <<<NCH, 1024, 0, stream>>>(deg, cbase);
  k_scanchunks<<<1, 64, 0, stream>>>(cbase, offs + NN);
  k_offs      <<<NCH, 1024, 0, stream>>>(deg, cbase, offs, dinv);
  k_fill      <<<EE / 256, 256, 0, stream>>>(ei, flags, offs, fill, dinv, ep);

  k_embed     <<<NBLK, 128, 0, stream>>>(x, whi, wlo, bE, flags, hb, bnsum, bnsq);
  k_bnfin     <<<1, 64, 0, stream>>>(bnsum, bnsq, gam, bet, flags, bnab);

  k_sp1<<<NN / 4, 256, 0, stream>>>(offs, ep, hb, bnab, diag2, zhi, zlo);
  k_sp2<<<NN / 4, 256, 0, stream>>>(offs, ep, diag2, zhi, zlo, curb);
  k_spg<<<NN / 4, 256, 0, stream>>>(offs, ep, curb, 64, diag2, nullptr, zhi, zlo, 192);
  k_spg<<<NN / 4, 256, 0, stream>>>(offs, ep, zhi + 192, ZD, diag2, curb, zhi, zlo, 256);

  k_final<<<(NN / 32 + 3) / 4, 256, 0, stream>>>(zhi, zlo, w1hi, w1lo, b1,
                                                 w2hi, w2lo, b2, flags, d_out);
}